// Round 1
// baseline (325.023 us; speedup 1.0000x reference)
//
#include <hip/hip_runtime.h>
#include <hip/hip_bf16.h>

#define EMBED 768
#define HEADS 12
#define WIN 64
#define DH 64   // EMBED/HEADS

typedef unsigned short u16;
typedef unsigned int u32;
typedef __attribute__((ext_vector_type(8))) short bf16x8;
typedef __attribute__((ext_vector_type(4))) float f32x4;

__device__ __forceinline__ u16 f2bf(float f) {
  union { float f; u32 u; } x; x.f = f;
  return (u16)((x.u + 0x7fffu + ((x.u >> 16) & 1u)) >> 16);
}

// ---------------- fp32 -> bf16 convert (vectorized float4 -> ushort4) ----------------
__global__ void cvt_f32_bf16(const float* __restrict__ in, u16* __restrict__ out, int n4) {
  int i = blockIdx.x * blockDim.x + threadIdx.x;
  if (i >= n4) return;
  float4 v = ((const float4*)in)[i];
  ushort4 o;
  o.x = f2bf(v.x); o.y = f2bf(v.y); o.z = f2bf(v.z); o.w = f2bf(v.w);
  ((ushort4*)out)[i] = o;
}

// ---------------- NT GEMM: C[M,N] = A[M,K] * B[N,K]^T + bias ----------------
// 128x128 tile, BK=64, 4 waves (2x2), 4x4 16x16x32 MFMA frags per wave.
// Staging via global_load_lds width 16 (linear LDS layout, wave-uniform base).
template<bool OUT_F32>
__global__ __launch_bounds__(256, 2)
void gemm_nt(const u16* __restrict__ A, const u16* __restrict__ Bw,
             const float* __restrict__ bias, void* __restrict__ Cout,
             int M, int N, int K) {
  __shared__ u16 As[128 * 64];
  __shared__ u16 Bs[128 * 64];
  const int nbx = N >> 7;
  const int brow = (blockIdx.x / nbx) << 7;
  const int bcol = (blockIdx.x % nbx) << 7;
  const int tid = threadIdx.x;
  const int wid = tid >> 6;
  const int lane = tid & 63;
  const int wr = wid >> 1, wc = wid & 1;

  f32x4 acc[4][4];
#pragma unroll
  for (int m = 0; m < 4; ++m)
#pragma unroll
    for (int n = 0; n < 4; ++n) acc[m][n] = (f32x4){0.f, 0.f, 0.f, 0.f};

  const u16* Ab = A + (size_t)brow * K;
  const u16* Bb = Bw + (size_t)bcol * K;
  const int l8 = lane >> 3;   // sub-row within 1KB chunk (0..7)
  const int c8 = lane & 7;    // 16B column chunk (0..7)

  for (int kt = 0; kt < K; kt += 64) {
#pragma unroll
    for (int c = 0; c < 4; ++c) {
      const int chunk = (c << 2) + wid;          // 0..15, wave-uniform
      const int row = (chunk << 3) + l8;         // tile row 0..127
      const u16* ga = Ab + (size_t)row * K + kt + (c8 << 3);
      const u16* gb = Bb + (size_t)row * K + kt + (c8 << 3);
      __builtin_amdgcn_global_load_lds(
          (const __attribute__((address_space(1))) void*)ga,
          (__attribute__((address_space(3))) void*)(As + (chunk << 9)), 16, 0, 0);
      __builtin_amdgcn_global_load_lds(
          (const __attribute__((address_space(1))) void*)gb,
          (__attribute__((address_space(3))) void*)(Bs + (chunk << 9)), 16, 0, 0);
    }
    __syncthreads();
#pragma unroll
    for (int kk = 0; kk < 2; ++kk) {
      bf16x8 af[4], bfr[4];
      const int kb = (kk << 5) + ((lane >> 4) << 3);   // element offset in row
#pragma unroll
      for (int m = 0; m < 4; ++m)
        af[m] = *(const bf16x8*)(As + ((wr << 6) + (m << 4) + (lane & 15)) * 64 + kb);
#pragma unroll
      for (int n = 0; n < 4; ++n)
        bfr[n] = *(const bf16x8*)(Bs + ((wc << 6) + (n << 4) + (lane & 15)) * 64 + kb);
#pragma unroll
      for (int m = 0; m < 4; ++m)
#pragma unroll
        for (int n = 0; n < 4; ++n)
          acc[m][n] = __builtin_amdgcn_mfma_f32_16x16x32_bf16(af[m], bfr[n], acc[m][n], 0, 0, 0);
    }
    __syncthreads();
  }

  const int row0 = brow + (wr << 6);
  const int col0 = bcol + (wc << 6);
#pragma unroll
  for (int n = 0; n < 4; ++n) {
    const int gc = col0 + (n << 4) + (lane & 15);
    const float bv = bias[gc];
#pragma unroll
    for (int m = 0; m < 4; ++m) {
#pragma unroll
      for (int r = 0; r < 4; ++r) {
        const int gr = row0 + (m << 4) + ((lane >> 4) << 2) + r;
        const float v = acc[m][n][r] + bv;
        if (OUT_F32) ((float*)Cout)[(size_t)gr * N + gc] = v;
        else ((u16*)Cout)[(size_t)gr * N + gc] = f2bf(v);
      }
    }
  }
}

// ---------------- Window attention: one block per (window, head) ----------------
// Q,K linear in LDS (pad 72); V transposed on load; softmax in registers via
// 16-lane shfl reduction on the MFMA C layout; O overwrites Q buffer in place.
__global__ __launch_bounds__(256, 2)
void win_attn(const u16* __restrict__ Qg, const u16* __restrict__ Kg,
              const u16* __restrict__ Vg, u16* __restrict__ Og) {
  __shared__ u16 Qs[64 * 72], Ks[64 * 72], Vt[64 * 72], Ps[64 * 72];
  const int bid = blockIdx.x;
  const int h = bid % HEADS;
  const int gw = bid / HEADS;                    // global window index (0..511)
  const size_t base = (size_t)gw * WIN * EMBED + (size_t)h * DH;
  const int tid = threadIdx.x;
  const int wid = tid >> 6, lane = tid & 63;

  // load Q,K linear; V transposed
#pragma unroll
  for (int cc = 0; cc < 2; ++cc) {
    const int c = tid + (cc << 8);               // 0..511
    const int row = c >> 3, col8 = c & 7;
    const size_t goff = base + (size_t)row * EMBED + (col8 << 3);
    uint4 q4 = *(const uint4*)(Qg + goff);
    uint4 k4 = *(const uint4*)(Kg + goff);
    uint4 v4 = *(const uint4*)(Vg + goff);
    *(uint4*)(Qs + row * 72 + (col8 << 3)) = q4;
    *(uint4*)(Ks + row * 72 + (col8 << 3)) = k4;
    const u16* vp = (const u16*)&v4;
#pragma unroll
    for (int j = 0; j < 8; ++j)
      Vt[((col8 << 3) + j) * 72 + row] = vp[j];
  }
  __syncthreads();

  // S = Q K^T * (1/8) : wave wid owns S rows [wid*16, wid*16+16)
  f32x4 sacc[4];
#pragma unroll
  for (int t = 0; t < 4; ++t) sacc[t] = (f32x4){0.f, 0.f, 0.f, 0.f};
  const int arow = (wid << 4) + (lane & 15);
  const int kb = ((lane >> 4) << 3);
  bf16x8 qf0 = *(const bf16x8*)(Qs + arow * 72 + kb);
  bf16x8 qf1 = *(const bf16x8*)(Qs + arow * 72 + 32 + kb);
#pragma unroll
  for (int t = 0; t < 4; ++t) {
    const int krow = (t << 4) + (lane & 15);
    bf16x8 kf0 = *(const bf16x8*)(Ks + krow * 72 + kb);
    bf16x8 kf1 = *(const bf16x8*)(Ks + krow * 72 + 32 + kb);
    sacc[t] = __builtin_amdgcn_mfma_f32_16x16x32_bf16(qf0, kf0, sacc[t], 0, 0, 0);
    sacc[t] = __builtin_amdgcn_mfma_f32_16x16x32_bf16(qf1, kf1, sacc[t], 0, 0, 0);
  }

  // softmax over 64 cols. row r of S lives in 16 lanes (same lane>>4 group), reg r&3.
#pragma unroll
  for (int t = 0; t < 4; ++t)
#pragma unroll
    for (int r = 0; r < 4; ++r) sacc[t][r] *= 0.125f;

#pragma unroll
  for (int r = 0; r < 4; ++r) {
    float m0 = fmaxf(fmaxf(sacc[0][r], sacc[1][r]), fmaxf(sacc[2][r], sacc[3][r]));
#pragma unroll
    for (int msk = 1; msk < 16; msk <<= 1) m0 = fmaxf(m0, __shfl_xor(m0, msk));
    float s0 = 0.f;
#pragma unroll
    for (int t = 0; t < 4; ++t) {
      float e = __expf(sacc[t][r] - m0);
      sacc[t][r] = e;
      s0 += e;
    }
#pragma unroll
    for (int msk = 1; msk < 16; msk <<= 1) s0 += __shfl_xor(s0, msk);
    const float inv = 1.f / s0;
#pragma unroll
    for (int t = 0; t < 4; ++t) sacc[t][r] *= inv;
  }

  // write P (bf16) to LDS in row-major layout for the PV A-operand
#pragma unroll
  for (int t = 0; t < 4; ++t)
#pragma unroll
    for (int r = 0; r < 4; ++r)
      Ps[((wid << 4) + ((lane >> 4) << 2) + r) * 72 + (t << 4) + (lane & 15)] = f2bf(sacc[t][r]);

  // O = P V : same-wave LDS write->read (compiler inserts lgkmcnt)
  f32x4 oacc[4];
#pragma unroll
  for (int t = 0; t < 4; ++t) oacc[t] = (f32x4){0.f, 0.f, 0.f, 0.f};
  const int prow = (wid << 4) + (lane & 15);
  bf16x8 pf0 = *(const bf16x8*)(Ps + prow * 72 + kb);
  bf16x8 pf1 = *(const bf16x8*)(Ps + prow * 72 + 32 + kb);
#pragma unroll
  for (int t = 0; t < 4; ++t) {
    const int vrow = (t << 4) + (lane & 15);     // output col d
    bf16x8 vf0 = *(const bf16x8*)(Vt + vrow * 72 + kb);
    bf16x8 vf1 = *(const bf16x8*)(Vt + vrow * 72 + 32 + kb);
    oacc[t] = __builtin_amdgcn_mfma_f32_16x16x32_bf16(pf0, vf0, oacc[t], 0, 0, 0);
    oacc[t] = __builtin_amdgcn_mfma_f32_16x16x32_bf16(pf1, vf1, oacc[t], 0, 0, 0);
  }

#pragma unroll
  for (int t = 0; t < 4; ++t)
#pragma unroll
    for (int r = 0; r < 4; ++r) {
      const int row = (wid << 4) + ((lane >> 4) << 2) + r;
      const int col = (t << 4) + (lane & 15);
      Og[base + (size_t)row * EMBED + col] = f2bf(oacc[t][r]);
    }
}

extern "C" void kernel_launch(void* const* d_in, const int* in_sizes, int n_in,
                              void* d_out, int out_size, void* d_ws, size_t ws_size,
                              hipStream_t stream) {
  const float* q  = (const float*)d_in[0];
  const float* Wq = (const float*)d_in[3];
  const float* bq = (const float*)d_in[4];
  const float* Wk = (const float*)d_in[5];
  const float* bk = (const float*)d_in[6];
  const float* Wv = (const float*)d_in[7];
  const float* bv = (const float*)d_in[8];
  const float* Wo = (const float*)d_in[9];
  const float* bo = (const float*)d_in[10];

  const int C = EMBED;
  const int M = in_sizes[0] / C;                 // 32768 rows total
  const size_t xsz = (size_t)M * C;              // 25,165,824
  const size_t wsz = (size_t)C * C;              // 589,824

  // X (bf16) lives in d_out scratch space (overwritten by the final GEMM).
  u16* Xb = (u16*)d_out;
  u16* Qb = (u16*)d_ws;
  u16* Kb = Qb + xsz;
  u16* Vb = Kb + xsz;
  u16* Wqb = Vb + xsz;
  u16* Wkb = Wqb + wsz;
  u16* Wvb = Wkb + wsz;
  u16* Wob = Wvb + wsz;

  {
    int n4 = (int)(xsz >> 2);
    cvt_f32_bf16<<<(n4 + 255) / 256, 256, 0, stream>>>(q, Xb, n4);
    int w4 = (int)(wsz >> 2);
    cvt_f32_bf16<<<(w4 + 255) / 256, 256, 0, stream>>>(Wq, Wqb, w4);
    cvt_f32_bf16<<<(w4 + 255) / 256, 256, 0, stream>>>(Wk, Wkb, w4);
    cvt_f32_bf16<<<(w4 + 255) / 256, 256, 0, stream>>>(Wv, Wvb, w4);
    cvt_f32_bf16<<<(w4 + 255) / 256, 256, 0, stream>>>(Wo, Wob, w4);
  }

  dim3 gg((M / 128) * (C / 128));                // 256 * 6 = 1536 blocks
  gemm_nt<false><<<gg, 256, 0, stream>>>(Xb, Wqb, bq, Qb, M, C, C);
  gemm_nt<false><<<gg, 256, 0, stream>>>(Xb, Wkb, bk, Kb, M, C, C);
  gemm_nt<false><<<gg, 256, 0, stream>>>(Xb, Wvb, bv, Vb, M, C, C);

  const int nwin = M / WIN;                      // 512 windows
  win_attn<<<nwin * HEADS, 256, 0, stream>>>(Qb, Kb, Vb, Qb);

  gemm_nt<true><<<gg, 256, 0, stream>>>(Qb, Wob, bo, d_out, M, C, C);
}

// Round 2
// 273.670 us; speedup vs baseline: 1.1876x; 1.1876x over previous
//
#include <hip/hip_runtime.h>
#include <hip/hip_bf16.h>

#define EMBED 768
#define HEADS 12
#define WIN 64
#define DH 64   // EMBED/HEADS

typedef unsigned short u16;
typedef unsigned int u32;
typedef __attribute__((ext_vector_type(8))) short bf16x8;
typedef __attribute__((ext_vector_type(4))) float f32x4;

__device__ __forceinline__ u16 f2bf(float f) {
  union { float f; u32 u; } x; x.f = f;
  return (u16)((x.u + 0x7fffu + ((x.u >> 16) & 1u)) >> 16);
}

// ---------------- fp32 -> bf16 convert (vectorized float4 -> ushort4) ----------------
__global__ void cvt_f32_bf16(const float* __restrict__ in, u16* __restrict__ out, int n4) {
  int i = blockIdx.x * blockDim.x + threadIdx.x;
  if (i >= n4) return;
  float4 v = ((const float4*)in)[i];
  ushort4 o;
  o.x = f2bf(v.x); o.y = f2bf(v.y); o.z = f2bf(v.z); o.w = f2bf(v.w);
  ((ushort4*)out)[i] = o;
}

// concat 3x768 biases into one 2304 buffer
__global__ void concat_bias(const float* __restrict__ bq, const float* __restrict__ bk,
                            const float* __restrict__ bv, float* __restrict__ out) {
  int i = blockIdx.x * 256 + threadIdx.x;     // 0..2303
  if (i < 768) out[i] = bq[i];
  else if (i < 1536) out[i] = bk[i - 768];
  else if (i < 2304) out[i] = bv[i - 1536];
}

// ---------------- NT GEMM: C[M,N] = A[M,K] * B[N,K]^T + bias ----------------
// 128x128 tile, BK=64, 4 waves (2x2), 4x4 16x16x32 MFMA frags/wave.
// global_load_lds width-16 staging (linear LDS); coalesced epilogue via LDS;
// XCD-aware block swizzle (grid % 8 == 0 required).
// OUT_F32=false: QKV-fused mode -> split columns into dQ/dK/dV (stride 768, bf16).
// OUT_F32=true : single f32 output dF (stride N).
template<bool OUT_F32>
__global__ __launch_bounds__(256, 3)
void gemm_nt(const u16* __restrict__ A, const u16* __restrict__ Bw,
             const float* __restrict__ bias,
             u16* __restrict__ dQ, u16* __restrict__ dK, u16* __restrict__ dV,
             float* __restrict__ dF, int N, int K) {
  __shared__ u16 smem[17408];                  // 34816 B: staging (32KB) / epilogue tile
  u16* As = smem;
  u16* Bs = smem + 8192;

  const int nbx = N >> 7;
  const int cpx = gridDim.x >> 3;              // blocks per XCD chunk
  int bid = blockIdx.x;
  bid = (bid & 7) * cpx + (bid >> 3);          // XCD swizzle (bijective: grid%8==0)
  const int brow = (bid / nbx) << 7;
  const int bcol = (bid % nbx) << 7;
  const int tid = threadIdx.x;
  const int wid = tid >> 6;
  const int lane = tid & 63;
  const int wr = wid >> 1, wc = wid & 1;

  f32x4 acc[4][4];
#pragma unroll
  for (int m = 0; m < 4; ++m)
#pragma unroll
    for (int n = 0; n < 4; ++n) acc[m][n] = (f32x4){0.f, 0.f, 0.f, 0.f};

  const u16* Ab = A + (size_t)brow * K;
  const u16* Bb = Bw + (size_t)bcol * K;
  const int l8 = lane >> 3;   // sub-row within 1KB chunk (0..7)
  const int c8 = lane & 7;    // 16B column chunk (0..7)

  for (int kt = 0; kt < K; kt += 64) {
#pragma unroll
    for (int c = 0; c < 4; ++c) {
      const int chunk = (c << 2) + wid;          // 0..15, wave-uniform
      const int row = (chunk << 3) + l8;         // tile row 0..127
      const u16* ga = Ab + (size_t)row * K + kt + (c8 << 3);
      const u16* gb = Bb + (size_t)row * K + kt + (c8 << 3);
      __builtin_amdgcn_global_load_lds(
          (const __attribute__((address_space(1))) void*)ga,
          (__attribute__((address_space(3))) void*)(As + (chunk << 9)), 16, 0, 0);
      __builtin_amdgcn_global_load_lds(
          (const __attribute__((address_space(1))) void*)gb,
          (__attribute__((address_space(3))) void*)(Bs + (chunk << 9)), 16, 0, 0);
    }
    __syncthreads();
#pragma unroll
    for (int kk = 0; kk < 2; ++kk) {
      bf16x8 af[4], bfr[4];
      const int kb = (kk << 5) + ((lane >> 4) << 3);
#pragma unroll
      for (int m = 0; m < 4; ++m)
        af[m] = *(const bf16x8*)(As + ((wr << 6) + (m << 4) + (lane & 15)) * 64 + kb);
#pragma unroll
      for (int n = 0; n < 4; ++n)
        bfr[n] = *(const bf16x8*)(Bs + ((wc << 6) + (n << 4) + (lane & 15)) * 64 + kb);
#pragma unroll
      for (int m = 0; m < 4; ++m)
#pragma unroll
        for (int n = 0; n < 4; ++n)
          acc[m][n] = __builtin_amdgcn_mfma_f32_16x16x32_bf16(af[m], bfr[n], acc[m][n], 0, 0, 0);
    }
    __syncthreads();
  }

  if (!OUT_F32) {
    // ---- bf16 QKV epilogue: stage 128x128 bf16 tile (stride 136), coalesced store ----
#pragma unroll
    for (int n = 0; n < 4; ++n) {
      const float bv = bias[bcol + (wc << 6) + (n << 4) + (lane & 15)];
#pragma unroll
      for (int m = 0; m < 4; ++m)
#pragma unroll
        for (int r = 0; r < 4; ++r) {
          const int rl = (wr << 6) + (m << 4) + ((lane >> 4) << 2) + r;
          const int cl = (wc << 6) + (n << 4) + (lane & 15);
          smem[rl * 136 + cl] = f2bf(acc[m][n][r] + bv);
        }
    }
    __syncthreads();
    const int seg = bcol / 768;
    const int colbase = bcol - seg * 768;
    u16* dst = (seg == 0) ? dQ : (seg == 1) ? dK : dV;
#pragma unroll
    for (int it = 0; it < 8; ++it) {
      const int row = (it << 4) + (tid >> 4);
      const int chunk = tid & 15;
      uint4 v = *(const uint4*)(smem + row * 136 + (chunk << 3));
      *(uint4*)(dst + (size_t)(brow + row) * 768 + colbase + (chunk << 3)) = v;
    }
  } else {
    // ---- f32 epilogue: two passes of 64 rows (stride 132 f32), coalesced float4 store ----
    float* Lf = (float*)smem;
#pragma unroll
    for (int p = 0; p < 2; ++p) {
      if (p) __syncthreads();                    // protect against previous readout
#pragma unroll
      for (int mh = 0; mh < 2; ++mh) {
        const int m = (p << 1) + mh;
#pragma unroll
        for (int n = 0; n < 4; ++n) {
          const float bv = bias[bcol + (wc << 6) + (n << 4) + (lane & 15)];
#pragma unroll
          for (int r = 0; r < 4; ++r) {
            const int lr = (wr << 5) + (mh << 4) + ((lane >> 4) << 2) + r;
            Lf[lr * 132 + (wc << 6) + (n << 4) + (lane & 15)] = acc[m][n][r] + bv;
          }
        }
      }
      __syncthreads();
#pragma unroll
      for (int it = 0; it < 8; ++it) {
        const int lr = (it << 3) + (tid >> 5);
        const int chunk = tid & 31;
        float4 v = *(const float4*)(Lf + lr * 132 + (chunk << 2));
        const int gr = brow + ((lr >> 5) << 6) + (((p << 1) + ((lr >> 4) & 1)) << 4) + (lr & 15);
        *(float4*)(dF + (size_t)gr * N + bcol + (chunk << 2)) = v;
      }
    }
  }
}

// ---------------- Window attention: one block per (window, head) ----------------
__global__ __launch_bounds__(256, 4)
void win_attn(const u16* __restrict__ Qg, const u16* __restrict__ Kg,
              const u16* __restrict__ Vg, u16* __restrict__ Og) {
  __shared__ u16 Qs[64 * 72], Ks[64 * 72], Vt[64 * 72], Ps[64 * 72];
  const int cpx = gridDim.x >> 3;
  int bid = blockIdx.x;
  bid = (bid & 7) * cpx + (bid >> 3);            // XCD swizzle (6144 % 8 == 0)
  const int h = bid % HEADS;
  const int gw = bid / HEADS;
  const size_t base = (size_t)gw * WIN * EMBED + (size_t)h * DH;
  const int tid = threadIdx.x;
  const int wid = tid >> 6, lane = tid & 63;

#pragma unroll
  for (int cc = 0; cc < 2; ++cc) {
    const int c = tid + (cc << 8);
    const int row = c >> 3, col8 = c & 7;
    const size_t goff = base + (size_t)row * EMBED + (col8 << 3);
    uint4 q4 = *(const uint4*)(Qg + goff);
    uint4 k4 = *(const uint4*)(Kg + goff);
    uint4 v4 = *(const uint4*)(Vg + goff);
    *(uint4*)(Qs + row * 72 + (col8 << 3)) = q4;
    *(uint4*)(Ks + row * 72 + (col8 << 3)) = k4;
    const u16* vp = (const u16*)&v4;
#pragma unroll
    for (int j = 0; j < 8; ++j)
      Vt[((col8 << 3) + j) * 72 + row] = vp[j];
  }
  __syncthreads();

  f32x4 sacc[4];
#pragma unroll
  for (int t = 0; t < 4; ++t) sacc[t] = (f32x4){0.f, 0.f, 0.f, 0.f};
  const int arow = (wid << 4) + (lane & 15);
  const int kb = ((lane >> 4) << 3);
  bf16x8 qf0 = *(const bf16x8*)(Qs + arow * 72 + kb);
  bf16x8 qf1 = *(const bf16x8*)(Qs + arow * 72 + 32 + kb);
#pragma unroll
  for (int t = 0; t < 4; ++t) {
    const int krow = (t << 4) + (lane & 15);
    bf16x8 kf0 = *(const bf16x8*)(Ks + krow * 72 + kb);
    bf16x8 kf1 = *(const bf16x8*)(Ks + krow * 72 + 32 + kb);
    sacc[t] = __builtin_amdgcn_mfma_f32_16x16x32_bf16(qf0, kf0, sacc[t], 0, 0, 0);
    sacc[t] = __builtin_amdgcn_mfma_f32_16x16x32_bf16(qf1, kf1, sacc[t], 0, 0, 0);
  }

#pragma unroll
  for (int t = 0; t < 4; ++t)
#pragma unroll
    for (int r = 0; r < 4; ++r) sacc[t][r] *= 0.125f;

#pragma unroll
  for (int r = 0; r < 4; ++r) {
    float m0 = fmaxf(fmaxf(sacc[0][r], sacc[1][r]), fmaxf(sacc[2][r], sacc[3][r]));
#pragma unroll
    for (int msk = 1; msk < 16; msk <<= 1) m0 = fmaxf(m0, __shfl_xor(m0, msk));
    float s0 = 0.f;
#pragma unroll
    for (int t = 0; t < 4; ++t) {
      float e = __expf(sacc[t][r] - m0);
      sacc[t][r] = e;
      s0 += e;
    }
#pragma unroll
    for (int msk = 1; msk < 16; msk <<= 1) s0 += __shfl_xor(s0, msk);
    const float inv = 1.f / s0;
#pragma unroll
    for (int t = 0; t < 4; ++t) sacc[t][r] *= inv;
  }

#pragma unroll
  for (int t = 0; t < 4; ++t)
#pragma unroll
    for (int r = 0; r < 4; ++r)
      Ps[((wid << 4) + ((lane >> 4) << 2) + r) * 72 + (t << 4) + (lane & 15)] = f2bf(sacc[t][r]);

  f32x4 oacc[4];
#pragma unroll
  for (int t = 0; t < 4; ++t) oacc[t] = (f32x4){0.f, 0.f, 0.f, 0.f};
  const int prow = (wid << 4) + (lane & 15);
  bf16x8 pf0 = *(const bf16x8*)(Ps + prow * 72 + kb);
  bf16x8 pf1 = *(const bf16x8*)(Ps + prow * 72 + 32 + kb);
#pragma unroll
  for (int t = 0; t < 4; ++t) {
    const int vrow = (t << 4) + (lane & 15);
    bf16x8 vf0 = *(const bf16x8*)(Vt + vrow * 72 + kb);
    bf16x8 vf1 = *(const bf16x8*)(Vt + vrow * 72 + 32 + kb);
    oacc[t] = __builtin_amdgcn_mfma_f32_16x16x32_bf16(pf0, vf0, oacc[t], 0, 0, 0);
    oacc[t] = __builtin_amdgcn_mfma_f32_16x16x32_bf16(pf1, vf1, oacc[t], 0, 0, 0);
  }

#pragma unroll
  for (int t = 0; t < 4; ++t)
#pragma unroll
    for (int r = 0; r < 4; ++r) {
      const int row = (wid << 4) + ((lane >> 4) << 2) + r;
      const int col = (t << 4) + (lane & 15);
      Og[base + (size_t)row * EMBED + col] = f2bf(oacc[t][r]);
    }
}

extern "C" void kernel_launch(void* const* d_in, const int* in_sizes, int n_in,
                              void* d_out, int out_size, void* d_ws, size_t ws_size,
                              hipStream_t stream) {
  const float* q  = (const float*)d_in[0];
  const float* Wq = (const float*)d_in[3];
  const float* bq = (const float*)d_in[4];
  const float* Wk = (const float*)d_in[5];
  const float* bk = (const float*)d_in[6];
  const float* Wv = (const float*)d_in[7];
  const float* bv = (const float*)d_in[8];
  const float* Wo = (const float*)d_in[9];
  const float* bo = (const float*)d_in[10];

  const int C = EMBED;
  const int M = in_sizes[0] / C;                 // 32768
  const size_t xsz = (size_t)M * C;
  const size_t wsz = (size_t)C * C;

  u16* Xb = (u16*)d_out;                         // scratch in d_out (overwritten by Wo GEMM)
  u16* Qb = (u16*)d_ws;
  u16* Kb = Qb + xsz;
  u16* Vb = Kb + xsz;
  u16* Wqkv = Vb + xsz;                          // 3*wsz bf16, rows = output cols 0..2303
  u16* Wob = Wqkv + 3 * wsz;
  float* biasc = (float*)(Wob + wsz);            // 2304 f32

  {
    int n4 = (int)(xsz >> 2);
    cvt_f32_bf16<<<(n4 + 255) / 256, 256, 0, stream>>>(q, Xb, n4);
    int w4 = (int)(wsz >> 2);
    cvt_f32_bf16<<<(w4 + 255) / 256, 256, 0, stream>>>(Wq, Wqkv, w4);
    cvt_f32_bf16<<<(w4 + 255) / 256, 256, 0, stream>>>(Wk, Wqkv + wsz, w4);
    cvt_f32_bf16<<<(w4 + 255) / 256, 256, 0, stream>>>(Wv, Wqkv + 2 * wsz, w4);
    cvt_f32_bf16<<<(w4 + 255) / 256, 256, 0, stream>>>(Wo, Wob, w4);
    concat_bias<<<9, 256, 0, stream>>>(bq, bk, bv, biasc);
  }

  // Fused QKV: C[32768 x 2304] = X * Wqkv^T, split into Q/K/V buffers
  {
    dim3 gg((M / 128) * (2304 / 128));           // 256*18 = 4608, %8==0
    gemm_nt<false><<<gg, 256, 0, stream>>>(Xb, Wqkv, biasc, Qb, Kb, Vb, nullptr, 2304, C);
  }

  const int nwin = M / WIN;
  win_attn<<<nwin * HEADS, 256, 0, stream>>>(Qb, Kb, Vb, Qb);

  // Output projection: f32 out
  {
    dim3 gg((M / 128) * (C / 128));              // 256*6 = 1536, %8==0
    gemm_nt<true><<<gg, 256, 0, stream>>>(Qb, Wob, bo, nullptr, nullptr, nullptr,
                                          (float*)d_out, C, C);
  }
}